// Round 9
// baseline (285.408 us; speedup 1.0000x reference)
//
#include <hip/hip_runtime.h>

#define HW 128
#define TW 32
#define TH 8

typedef __attribute__((ext_vector_type(2))) float f32x2;

__device__ __forceinline__ float lrelu(float x) { return x > 0.f ? x : 0.1f * x; }

// Static device scratch
__device__ float g_kern[32 * 64 * 9];   // att-folded depthwise kernels
__device__ float g_wT[64 * 64];         // g_wT[c*64+o] = conv_w[o*64+c]

// ---------------- prep: b<32 -> att-scaled kernels; b==32 -> W transpose ----------------
__global__ __launch_bounds__(64) void dgfem_prep(
    const float* __restrict__ v, const float* __restrict__ ca_w1,
    const float* __restrict__ ca_w2, const float* __restrict__ k_w1,
    const float* __restrict__ k_w2, const float* __restrict__ conv_w)
{
    const int b = blockIdx.x;
    const int t = threadIdx.x;           // 64 threads

    if (b == 32) {                       // transpose conv_w -> c-major rows
        for (int i = t; i < 4096; i += 64)
            g_wT[(i & 63) * 64 + (i >> 6)] = conv_w[i];
        return;
    }

    __shared__ float vb[64], t1[8], att[64], t2[64];
    vb[t] = v[b * 64 + t];
    __syncthreads();

    if (t < 8) {
        float s = 0.f;
        for (int j = 0; j < 64; ++j) s += vb[j] * ca_w1[t * 64 + j];
        t1[t] = lrelu(s);
    }
    {
        float s = 0.f;
        for (int j = 0; j < 64; ++j) s += vb[j] * k_w1[t * 64 + j];
        t2[t] = lrelu(s);
    }
    __syncthreads();
    {
        float s = 0.f;
        for (int i = 0; i < 8; ++i) s += t1[i] * ca_w2[t * 8 + i];
        att[t] = 1.f / (1.f + expf(-s));
    }
    __syncthreads();
    // fold att[c] into the kernel: conv(x*a, k) == conv(x, a*k)
    for (int r = t; r < 576; r += 64) {
        float s = 0.f;
        for (int j = 0; j < 64; ++j) s += t2[j] * k_w2[r * 64 + j];
        g_kern[b * 576 + r] = s * att[r / 9];
    }
}

// ---- fused: depthwise 3x3 (pipelined direct loads) + lrelu + 1x1 via v_pk_fma_f32 ----
__global__ __launch_bounds__(256) void dgfem_main(
    const float* __restrict__ x0, const float* __restrict__ conv_b,
    float* __restrict__ out)
{
    const int t  = threadIdx.x;          // 256 = 32x8 pixel tile, 1 px/thread
    const int b  = blockIdx.z;
    const int gx = blockIdx.x * TW + (t & (TW - 1));
    const int gy = blockIdx.y * TH + (t >> 5);

    // per-thread stencil geometry: 9 byte offsets + 9 masks (channel-invariant)
    int  offb[9];
    bool msk[9];
    #pragma unroll
    for (int dy = 0; dy < 3; ++dy)
        #pragma unroll
        for (int dx = 0; dx < 3; ++dx) {
            int xi = gx + dx - 1, yi = gy + dy - 1;
            bool in = ((unsigned)xi < HW) && ((unsigned)yi < HW);
            offb[dy * 3 + dx] = in ? (yi * HW + xi) * 4 : 0;
            msk[dy * 3 + dx] = in;
        }

    const size_t bbase = (size_t)b * 64 * (HW * HW);
    const char*  xb = (const char*)(x0 + bbase);
    const float* kb = g_kern + b * 576;

    f32x2 acc2[32];
    #pragma unroll
    for (int o = 0; o < 32; ++o) acc2[o] = (f32x2){0.f, 0.f};

    float xvA[2][9], xvB[2][9];

    // issue a 2-channel batch of tap loads (18 independent dwords)
    #define LOADX(buf, cbase)                                              \
    {                                                                      \
        const char* xc0 = xb + (size_t)(cbase) * 65536;                    \
        const char* xc1 = xc0 + 65536;                                     \
        _Pragma("unroll")                                                  \
        for (int tp = 0; tp < 9; ++tp) {                                   \
            buf[0][tp] = *(const float*)(xc0 + offb[tp]);                  \
            buf[1][tp] = *(const float*)(xc1 + offb[tp]);                  \
        }                                                                  \
    }

    // consume a 2-channel batch: dwconv + lrelu + 32 packed FMAs per channel
    #define CONSUME(buf, cbase)                                            \
    {                                                                      \
        _Pragma("unroll")                                                  \
        for (int jj = 0; jj < 2; ++jj) {                                   \
            const int c = (cbase) + jj;                                    \
            const float* kc = kb + c * 9;          /* uniform -> s_load */ \
            float a = 0.f;                                                 \
            _Pragma("unroll")                                              \
            for (int tp = 0; tp < 9; ++tp) {                               \
                float xm = msk[tp] ? buf[jj][tp] : 0.f;                    \
                a = fmaf(kc[tp], xm, a);                                   \
            }                                                              \
            a = lrelu(a);                                                  \
            const f32x2 ysp = (f32x2){a, a};                               \
            const double* wrow = (const double*)(g_wT + c * 64);           \
            _Pragma("unroll")                                              \
            for (int o2 = 0; o2 < 32; ++o2) {                              \
                double w8 = wrow[o2];              /* uniform -> SGPR pair */ \
                asm("v_pk_fma_f32 %0, %1, %2, %0"                          \
                    : "+v"(acc2[o2]) : "s"(w8), "v"(ysp));                 \
            }                                                              \
        }                                                                  \
    }

    LOADX(xvA, 0);
    #pragma unroll 1
    for (int cb = 0; cb < 16; ++cb) {
        const int c0 = cb * 4;
        LOADX(xvB, c0 + 2);
        __builtin_amdgcn_sched_barrier(0);   // pin B-loads before A-consume
        CONSUME(xvA, c0);
        LOADX(xvA, (c0 + 4) & 63);           // wraps to ch0 on last iter (unused)
        __builtin_amdgcn_sched_barrier(0);   // pin A-loads before B-consume
        CONSUME(xvB, c0 + 2);
    }

    float* op = out + bbase + (size_t)(gy * HW + gx);
    #pragma unroll
    for (int o2 = 0; o2 < 32; ++o2) {
        op[(size_t)(2 * o2)     * (HW * HW)] = acc2[o2].x + conv_b[2 * o2];
        op[(size_t)(2 * o2 + 1) * (HW * HW)] = acc2[o2].y + conv_b[2 * o2 + 1];
    }
    #undef LOADX
    #undef CONSUME
}

extern "C" void kernel_launch(void* const* d_in, const int* in_sizes, int n_in,
                              void* d_out, int out_size, void* d_ws, size_t ws_size,
                              hipStream_t stream) {
    const float* x0     = (const float*)d_in[0];
    const float* v      = (const float*)d_in[1];
    const float* ca_w1  = (const float*)d_in[2];
    const float* ca_w2  = (const float*)d_in[3];
    const float* k_w1   = (const float*)d_in[4];
    const float* k_w2   = (const float*)d_in[5];
    const float* conv_w = (const float*)d_in[6];
    const float* conv_b = (const float*)d_in[7];
    float* outp = (float*)d_out;

    dgfem_prep<<<dim3(33), dim3(64), 0, stream>>>(v, ca_w1, ca_w2, k_w1, k_w2, conv_w);
    dgfem_main<<<dim3(HW / TW, HW / TH, 32), dim3(256), 0, stream>>>(x0, conv_b, outp);
}

// Round 10
// 243.154 us; speedup vs baseline: 1.1738x; 1.1738x over previous
//
#include <hip/hip_runtime.h>

#define HW 128
#define TW 32
#define TH 8

__device__ __forceinline__ float lrelu(float x) { return x > 0.f ? x : 0.1f * x; }

// Static device scratch
__device__ float g_kern[32 * 64 * 9];   // att-folded depthwise kernels
__device__ float g_wT[64 * 64];         // g_wT[c*64+o] = conv_w[o*64+c]

// ---------------- prep: b<32 -> att-scaled kernels; b==32 -> W transpose ----------------
__global__ __launch_bounds__(64) void dgfem_prep(
    const float* __restrict__ v, const float* __restrict__ ca_w1,
    const float* __restrict__ ca_w2, const float* __restrict__ k_w1,
    const float* __restrict__ k_w2, const float* __restrict__ conv_w)
{
    const int b = blockIdx.x;
    const int t = threadIdx.x;           // 64 threads

    if (b == 32) {                       // transpose conv_w -> c-major rows
        for (int i = t; i < 4096; i += 64)
            g_wT[(i & 63) * 64 + (i >> 6)] = conv_w[i];
        return;
    }

    __shared__ float vb[64], t1[8], att[64], t2[64];
    vb[t] = v[b * 64 + t];
    __syncthreads();

    if (t < 8) {
        float s = 0.f;
        for (int j = 0; j < 64; ++j) s += vb[j] * ca_w1[t * 64 + j];
        t1[t] = lrelu(s);
    }
    {
        float s = 0.f;
        for (int j = 0; j < 64; ++j) s += vb[j] * k_w1[t * 64 + j];
        t2[t] = lrelu(s);
    }
    __syncthreads();
    {
        float s = 0.f;
        for (int i = 0; i < 8; ++i) s += t1[i] * ca_w2[t * 8 + i];
        att[t] = 1.f / (1.f + expf(-s));
    }
    __syncthreads();
    // fold att[c] into the kernel: conv(x*a, k) == conv(x, a*k)
    for (int r = t; r < 576; r += 64) {
        float s = 0.f;
        for (int j = 0; j < 64; ++j) s += t2[j] * k_w2[r * 64 + j];
        g_kern[b * 576 + r] = s * att[r / 9];
    }
}

// ---- fused: depthwise 3x3 (distance-2 pipelined loads) + lrelu + 1x1 (SGPR W) ----
__global__ __launch_bounds__(256) void dgfem_main(
    const float* __restrict__ x0, const float* __restrict__ conv_b,
    float* __restrict__ out)
{
    const int t  = threadIdx.x;          // 256 = 32x8 pixel tile, 1 px/thread
    const int b  = blockIdx.z;
    const int gx = blockIdx.x * TW + (t & (TW - 1));
    const int gy = blockIdx.y * TH + (t >> 5);

    // per-thread stencil geometry (channel-invariant)
    int  off[9];
    bool msk[9];
    bool allin = true;
    #pragma unroll
    for (int dy = 0; dy < 3; ++dy)
        #pragma unroll
        for (int dx = 0; dx < 3; ++dx) {
            int xi = gx + dx - 1, yi = gy + dy - 1;
            bool in = ((unsigned)xi < HW) && ((unsigned)yi < HW);
            off[dy * 3 + dx] = in ? (yi * HW + xi) : 0;
            msk[dy * 3 + dx] = in;
            allin = allin && in;
        }

    const size_t bbase = (size_t)b * 64 * (HW * HW);
    const float* xb = x0 + bbase;
    const float* kb = g_kern + b * 576;

    float acc[64];
    #pragma unroll
    for (int o = 0; o < 64; ++o) acc[o] = 0.f;

    float xvA[9], xvB[9], xvC[9], xvD[9];

    // issue one channel's 9 tap loads (independent, saddr+voffset)
    #define LOADX(buf, cc) do {                                            \
        const float* xc = xb + ((cc) << 14);                               \
        _Pragma("unroll")                                                  \
        for (int tp = 0; tp < 9; ++tp) buf[tp] = xc[off[tp]];              \
    } while (0)

    // consume one channel: dwconv (tree) + lrelu + 64 FMA vs SGPR weights
    #define CONSUME(buf, cc) do {                                          \
        const float* kc = kb + (cc) * 9;            /* uniform -> s_load */\
        float a0, a1, a2;                                                  \
        if (allin) {                                                       \
            a0 = fmaf(kc[0], buf[0], fmaf(kc[1], buf[1], kc[2] * buf[2])); \
            a1 = fmaf(kc[3], buf[3], fmaf(kc[4], buf[4], kc[5] * buf[5])); \
            a2 = fmaf(kc[6], buf[6], fmaf(kc[7], buf[7], kc[8] * buf[8])); \
        } else {                                                           \
            a0 = fmaf(kc[0], msk[0] ? buf[0] : 0.f,                        \
                 fmaf(kc[1], msk[1] ? buf[1] : 0.f,                        \
                      kc[2] * (msk[2] ? buf[2] : 0.f)));                   \
            a1 = fmaf(kc[3], msk[3] ? buf[3] : 0.f,                        \
                 fmaf(kc[4], msk[4] ? buf[4] : 0.f,                        \
                      kc[5] * (msk[5] ? buf[5] : 0.f)));                   \
            a2 = fmaf(kc[6], msk[6] ? buf[6] : 0.f,                        \
                 fmaf(kc[7], msk[7] ? buf[7] : 0.f,                        \
                      kc[8] * (msk[8] ? buf[8] : 0.f)));                   \
        }                                                                  \
        const float yv = lrelu(a0 + a1 + a2);                              \
        const float* wc = g_wT + (cc) * 64;         /* uniform -> s_load */\
        _Pragma("unroll")                                                  \
        for (int o = 0; o < 64; ++o) acc[o] = fmaf(wc[o], yv, acc[o]);     \
    } while (0)

    LOADX(xvA, 0);
    LOADX(xvB, 1);

    #pragma unroll 1
    for (int cb = 0; cb < 16; ++cb) {
        const int c0 = cb * 4;
        LOADX(xvC, c0 + 2);
        CONSUME(xvA, c0);
        LOADX(xvD, c0 + 3);
        CONSUME(xvB, c0 + 1);
        if (cb != 15) LOADX(xvA, c0 + 4);
        CONSUME(xvC, c0 + 2);
        if (cb != 15) LOADX(xvB, c0 + 5);
        CONSUME(xvD, c0 + 3);
    }
    #undef LOADX
    #undef CONSUME

    float* op = out + bbase + (size_t)(gy * HW + gx);
    #pragma unroll
    for (int o = 0; o < 64; ++o)
        op[(size_t)o * (HW * HW)] = acc[o] + conv_b[o];
}

extern "C" void kernel_launch(void* const* d_in, const int* in_sizes, int n_in,
                              void* d_out, int out_size, void* d_ws, size_t ws_size,
                              hipStream_t stream) {
    const float* x0     = (const float*)d_in[0];
    const float* v      = (const float*)d_in[1];
    const float* ca_w1  = (const float*)d_in[2];
    const float* ca_w2  = (const float*)d_in[3];
    const float* k_w1   = (const float*)d_in[4];
    const float* k_w2   = (const float*)d_in[5];
    const float* conv_w = (const float*)d_in[6];
    const float* conv_b = (const float*)d_in[7];
    float* outp = (float*)d_out;

    dgfem_prep<<<dim3(33), dim3(64), 0, stream>>>(v, ca_w1, ca_w2, k_w1, k_w2, conv_w);
    dgfem_main<<<dim3(HW / TW, HW / TH, 32), dim3(256), 0, stream>>>(x0, conv_b, outp);
}

// Round 11
// 96.409 us; speedup vs baseline: 2.9604x; 2.5221x over previous
//
#include <hip/hip_runtime.h>

#define HW 128

typedef __attribute__((ext_vector_type(8))) short  bfrag;   // 8 bf16 (4 VGPRs)
typedef __attribute__((ext_vector_type(16))) float f16x;    // 32x32 accumulator

__device__ __forceinline__ float lrelu(float x) { return x > 0.f ? x : 0.1f * x; }

// RNE fp32 -> bf16 (prep only)
__device__ __forceinline__ short f2bf(float f) {
    unsigned u = __builtin_bit_cast(unsigned, f);
    u = u + 0x7FFFu + ((u >> 16) & 1u);
    return (short)(u >> 16);
}
__device__ __forceinline__ float bf2f(short s) {
    return __builtin_bit_cast(float, (unsigned)(unsigned short)s << 16);
}

// tap table [b][s][tap][j][g]  (c = s*16 + g*8 + j), att-folded
__device__ float g_ktab[32][4][9][8][2];
__device__ short g_whi[4096], g_wlo[4096];        // conv_w bf16 hi/lo, [o*64+c]

// ---------- prep: b<32 -> att-folded kernels; b==32 -> W hi/lo split ----------
__global__ __launch_bounds__(64) void dgfem_prep(
    const float* __restrict__ v, const float* __restrict__ ca_w1,
    const float* __restrict__ ca_w2, const float* __restrict__ k_w1,
    const float* __restrict__ k_w2, const float* __restrict__ conv_w)
{
    const int b = blockIdx.x;
    const int t = threadIdx.x;           // 64 threads

    if (b == 32) {                       // bf16 hi/lo decomposition of conv_w
        for (int i = t; i < 4096; i += 64) {
            float wv = conv_w[i];
            short hi = f2bf(wv);
            short lo = f2bf(wv - bf2f(hi));
            g_whi[i] = hi;
            g_wlo[i] = lo;
        }
        return;
    }

    __shared__ float vb[64], t1[8], att[64], t2[64];
    vb[t] = v[b * 64 + t];
    __syncthreads();

    if (t < 8) {
        float s = 0.f;
        for (int j = 0; j < 64; ++j) s += vb[j] * ca_w1[t * 64 + j];
        t1[t] = lrelu(s);
    }
    {
        float s = 0.f;
        for (int j = 0; j < 64; ++j) s += vb[j] * k_w1[t * 64 + j];
        t2[t] = lrelu(s);
    }
    __syncthreads();
    {
        float s = 0.f;
        for (int i = 0; i < 8; ++i) s += t1[i] * ca_w2[t * 8 + i];
        att[t] = 1.f / (1.f + expf(-s));
    }
    __syncthreads();
    // fold att[c] into kernel (conv(x*a,k) == conv(x,a*k))
    for (int r = t; r < 576; r += 64) {
        int c = r / 9, tp = r - c * 9;
        float s = 0.f;
        for (int j = 0; j < 64; ++j) s += t2[j] * k_w2[r * 64 + j];
        int ss = c >> 4, gg = (c >> 3) & 1, jj = c & 7;
        g_ktab[b][ss][tp][jj][gg] = s * att[c];
    }
}

// LDS byte layout: [pad 16][xbuf 2*24576][pad 16][ktab 2304]
#define XBf  4          // float index of xbuf base
#define KTf  12296      // float index of ktab base  ((16+49152+16)/4)

__global__ __launch_bounds__(256) void dgfem_main(
    const float* __restrict__ x0, const float* __restrict__ conv_b,
    float* __restrict__ out)
{
    const int t  = threadIdx.x;
    const int w  = t >> 6;               // wave id (px tile)
    const int l  = t & 63;
    const int g  = l >> 5;               // k-half
    const int ln = l & 31;               // col / A-row
    const int px = w * 32 + ln;

    // XCD swizzle: XCD k gets images 4k..4k+3, rows sequential
    const int bid  = blockIdx.x;
    const int orig = (bid & 7) * 512 + (bid >> 3);
    const int b    = orig >> 7;
    const int gy   = orig & 127;

    __shared__ __align__(16) char lds[51488];
    float* ldsf = (float*)lds;

    // row geometry (block-uniform)
    const int gym = gy > 0 ? gy - 1 : 0;
    const int gyp = gy < 127 ? gy + 1 : 127;
    const float rmask[3] = { gy > 0 ? 1.f : 0.f, 1.f, gy < 127 ? 1.f : 0.f };
    const int rowoff[3] = { gym * 512, gy * 512, gyp * 512 };   // bytes within channel

    // stage tap table with row masks folded in
    {
        const float* src = &g_ktab[b][0][0][0][0];
        for (int i = t; i < 576; i += 256) {
            int tp = (i >> 4) % 9;                  // [s][tap][j][g]: 16 floats per tap
            ldsf[KTf + i] = src[i] * rmask[tp / 3];
        }
    }

    const char* xb = (const char*)x0 + ((size_t)b << 22);
    const int lane4 = l * 4;

    // ---- staging macro: round rr -> buffer sel (wave w stages c_local 4w..4w+3) ----
    #define STAGE(rr, sel)                                                        \
    {                                                                             \
        _Pragma("unroll")                                                         \
        for (int q = 0; q < 4; ++q) {                                             \
            const int cl = 4 * w + q;                                             \
            const char* csrc = xb + (((rr) * 16 + cl) << 16);                     \
            _Pragma("unroll")                                                     \
            for (int dy = 0; dy < 3; ++dy) {                                      \
                _Pragma("unroll")                                                 \
                for (int h = 0; h < 2; ++h) {                                     \
                    const char* src = csrc + rowoff[dy] + h * 256 + lane4;        \
                    char* dst = lds + 16 + ((sel) * 24576 + cl * 1536             \
                                            + dy * 512 + h * 256);                \
                    __builtin_amdgcn_global_load_lds(                             \
                        (const __attribute__((address_space(1))) unsigned*)src,   \
                        (__attribute__((address_space(3))) unsigned*)dst,         \
                        4, 0, 0);                                                 \
                }                                                                 \
            }                                                                     \
        }                                                                         \
    }

    f16x acc0, acc1;
    #pragma unroll
    for (int i = 0; i < 16; ++i) { acc0[i] = 0.f; acc1[i] = 0.f; }

    const int woffb = ln * 128 + g * 16;             // W-row byte offset
    const float mLf = (px > 0)   ? 1.f : 0.f;
    const float mRf = (px < 127) ? 1.f : 0.f;

    STAGE(0, 0);
    __syncthreads();                                  // ktab + stage0 complete

    #pragma unroll
    for (int rr = 0; rr < 4; ++rr) {
        const int sel = rr & 1;
        if (rr < 3) STAGE(rr + 1, sel ^ 1);

        // ---- consume: 8 channels -> y (bf16 hi/lo) ----
        bfrag yhi, ylo;
        const int xbase = XBf + sel * 6144 + g * 3072 + px;
        const int kbase = KTf + rr * 144 + g;
        #pragma unroll
        for (int j = 0; j < 8; ++j) {
            const int xj = xbase + j * 384;
            float a = 0.f;
            #pragma unroll
            for (int dy = 0; dy < 3; ++dy) {
                const int xi = xj + dy * 128;
                float k0 = ldsf[kbase + ((dy * 3 + 0) * 8 + j) * 2];
                float k1 = ldsf[kbase + ((dy * 3 + 1) * 8 + j) * 2];
                float k2 = ldsf[kbase + ((dy * 3 + 2) * 8 + j) * 2];
                float xL = ldsf[xi - 1] * mLf;
                float xC = ldsf[xi];
                float xR = ldsf[xi + 1] * mRf;
                a = fmaf(k0, xL, fmaf(k1, xC, fmaf(k2, xR, a)));
            }
            a = lrelu(a);
            unsigned u  = __builtin_bit_cast(unsigned, a);
            float   hif = __builtin_bit_cast(float, u & 0xFFFF0000u);
            float   lof = a - hif;                   // exact residual
            yhi[j] = (short)(u >> 16);
            ylo[j] = (short)(__builtin_bit_cast(unsigned, lof) >> 16);
        }

        // ---- MFMA: W(hi/lo) x y(hi/lo), 3-term split ----
        const char* whb = (const char*)g_whi + woffb + rr * 32;
        const char* wlb = (const char*)g_wlo + woffb + rr * 32;
        bfrag whi0 = *(const bfrag*)(whb);
        bfrag whi1 = *(const bfrag*)(whb + 4096);
        bfrag wlo0 = *(const bfrag*)(wlb);
        bfrag wlo1 = *(const bfrag*)(wlb + 4096);

        acc0 = __builtin_amdgcn_mfma_f32_32x32x16_bf16(whi0, yhi, acc0, 0, 0, 0);
        acc0 = __builtin_amdgcn_mfma_f32_32x32x16_bf16(whi0, ylo, acc0, 0, 0, 0);
        acc0 = __builtin_amdgcn_mfma_f32_32x32x16_bf16(wlo0, yhi, acc0, 0, 0, 0);
        acc1 = __builtin_amdgcn_mfma_f32_32x32x16_bf16(whi1, yhi, acc1, 0, 0, 0);
        acc1 = __builtin_amdgcn_mfma_f32_32x32x16_bf16(whi1, ylo, acc1, 0, 0, 0);
        acc1 = __builtin_amdgcn_mfma_f32_32x32x16_bf16(wlo1, yhi, acc1, 0, 0, 0);

        if (rr < 3) __syncthreads();                 // drain stage rr+1, protect reuse
    }
    #undef STAGE

    // epilogue: D layout col=lane&31, row=(reg&3)+8*(reg>>2)+4*(lane>>5)  [verified 3x]
    float* ob = out + ((size_t)b << 20) + gy * HW + px;
    #pragma unroll
    for (int q = 0; q < 4; ++q) {
        const int obase = 8 * q + 4 * g;
        float4 b0 = *(const float4*)&conv_b[obase];
        float4 b1 = *(const float4*)&conv_b[32 + obase];
        const float* b0f = (const float*)&b0;
        const float* b1f = (const float*)&b1;
        #pragma unroll
        for (int rr = 0; rr < 4; ++rr) {
            ob[(size_t)(obase + rr) * 16384]      = acc0[q * 4 + rr] + b0f[rr];
            ob[(size_t)(32 + obase + rr) * 16384] = acc1[q * 4 + rr] + b1f[rr];
        }
    }
}

extern "C" void kernel_launch(void* const* d_in, const int* in_sizes, int n_in,
                              void* d_out, int out_size, void* d_ws, size_t ws_size,
                              hipStream_t stream) {
    const float* x0     = (const float*)d_in[0];
    const float* v      = (const float*)d_in[1];
    const float* ca_w1  = (const float*)d_in[2];
    const float* ca_w2  = (const float*)d_in[3];
    const float* k_w1   = (const float*)d_in[4];
    const float* k_w2   = (const float*)d_in[5];
    const float* conv_w = (const float*)d_in[6];
    const float* conv_b = (const float*)d_in[7];
    float* outp = (float*)d_out;

    dgfem_prep<<<dim3(33), dim3(64), 0, stream>>>(v, ca_w1, ca_w2, k_w1, k_w2, conv_w);
    dgfem_main<<<dim3(4096), dim3(256), 0, stream>>>(x0, conv_b, outp);
}